// Round 1
// baseline (11.396 us; speedup 1.0000x reference)
//
#include <hip/hip_runtime.h>

// QuantumAttention: analytic reduction of the 12-wire circuit.
//  - psi(wires0..7) = f1 (x) f2 : 256 complex amps / batch item, ancillas |0>.
//  - 8 Rot gates (2x2 complex), CZ ring = one sign mask, measurement circuit
//    == (I+SWAP)/2 projector on pairs (i, i+4)  [derived: CNOT*(I+CX)/2*CNOT].
//  - out[b] = || P_sym^(x)4 psi ||^2.
// Layout: wire w <-> bit (7-w) of flat index (reshape makes wire 0 the MSB).

__global__ __launch_bounds__(256) void qattn_kernel(const float* __restrict__ x,
                                                    const float* __restrict__ w,
                                                    float* __restrict__ out) {
    const int b   = blockIdx.x;
    const int tid = threadIdx.x;

    __shared__ float sr[256];
    __shared__ float si[256];
    __shared__ float umat[8][8];   // per gate: u00r,u00i,u01r,u01i,u10r,u10i,u11r,u11i
    __shared__ float wsum[4];

    // threads 0..7 each build one Rot matrix:
    //   Rot = [[ep*c, -em*s], [conj(em)*s, conj(ep)*c]],
    //   ep = exp(-0.5i(phi+om)), em = exp(0.5i(phi-om))
    if (tid < 8) {
        const float phi = w[tid * 3 + 0];
        const float th  = w[tid * 3 + 1];
        const float om  = w[tid * 3 + 2];
        float sh, ch;      sincosf(0.5f * th, &sh, &ch);
        float ep_i, ep_r;  sincosf(-0.5f * (phi + om), &ep_i, &ep_r);
        float em_i, em_r;  sincosf( 0.5f * (phi - om), &em_i, &em_r);
        umat[tid][0] =  ep_r * ch;   // u00 = ep*c
        umat[tid][1] =  ep_i * ch;
        umat[tid][2] = -em_r * sh;   // u01 = -em*s
        umat[tid][3] = -em_i * sh;
        umat[tid][4] =  em_r * sh;   // u10 = conj(em)*s
        umat[tid][5] = -em_i * sh;
        umat[tid][6] =  ep_r * ch;   // u11 = conj(ep)*c
        umat[tid][7] = -ep_i * ch;
    }

    // initial amplitude: f1[idx>>4] * f2[idx&15]  (real)
    const float* xb = x + b * 32;
    float ar = xb[tid >> 4] * xb[16 + (tid & 15)];
    float ai = 0.0f;

    // 8 single-qubit Rot gates; wire g acts on bit (7-g)
    for (int g = 0; g < 8; ++g) {
        sr[tid] = ar; si[tid] = ai;
        __syncthreads();                       // also publishes umat on g==0
        const int   mask = 1 << (7 - g);
        const float pr = sr[tid ^ mask];
        const float pi = si[tid ^ mask];
        const float u0r = umat[g][0], u0i = umat[g][1];
        const float u1r = umat[g][2], u1i = umat[g][3];
        const float u2r = umat[g][4], u2i = umat[g][5];
        const float u3r = umat[g][6], u3i = umat[g][7];
        float nr, ni;
        if ((tid & mask) == 0) {               // new0 = u00*a0 + u01*a1
            nr = u0r * ar - u0i * ai + u1r * pr - u1i * pi;
            ni = u0r * ai + u0i * ar + u1r * pi + u1i * pr;
        } else {                               // new1 = u10*a0 + u11*a1
            nr = u2r * pr - u2i * pi + u3r * ar - u3i * ai;
            ni = u2r * pi + u2i * pr + u3r * ai + u3i * ar;
        }
        ar = nr; ai = ni;
        __syncthreads();                       // reads done before next overwrite
    }

    // CZ ring on wires (0,1)..(6,7),(7,0): sign = parity of cyclic adjacent-bit ANDs
    {
        const unsigned t = (unsigned)tid;
        const unsigned u = ((t >> 1) | (t << 7)) & 0xffu;
        if (__popc(t & u) & 1) { ar = -ar; ai = -ai; }
    }

    // P_sym = (I+SWAP)/2 on bit pairs (7,3),(6,2),(5,1),(4,0)
    const int masks[4] = {0x88, 0x44, 0x22, 0x11};
#pragma unroll
    for (int p = 0; p < 4; ++p) {
        sr[tid] = ar; si[tid] = ai;
        __syncthreads();
        const int m = masks[p];
        const int t = tid & m;
        if (t != 0 && t != m) {                // bits differ -> average with swap
            ar = 0.5f * (ar + sr[tid ^ m]);
            ai = 0.5f * (ai + si[tid ^ m]);
        }
        __syncthreads();
    }

    // norm^2 reduction: wave64 shuffle + cross-wave LDS
    float val = ar * ar + ai * ai;
#pragma unroll
    for (int off = 32; off > 0; off >>= 1) val += __shfl_down(val, off, 64);
    if ((tid & 63) == 0) wsum[tid >> 6] = val;
    __syncthreads();
    if (tid == 0) out[b] = wsum[0] + wsum[1] + wsum[2] + wsum[3];
}

extern "C" void kernel_launch(void* const* d_in, const int* in_sizes, int n_in,
                              void* d_out, int out_size, void* d_ws, size_t ws_size,
                              hipStream_t stream) {
    const float* x   = (const float*)d_in[0];   // (2048, 32) f32, rows pre-normalized
    const float* w   = (const float*)d_in[1];   // (1, 8, 3) f32
    float*       out = (float*)d_out;           // (2048,) f32
    qattn_kernel<<<out_size, 256, 0, stream>>>(x, w, out);
}

// Round 2
// 9.666 us; speedup vs baseline: 1.1790x; 1.1790x over previous
//
#include <hip/hip_runtime.h>

// QuantumAttention, analytic reduction (see round-0 derivation):
//   out[b] = || P_sym^(x)4 · (CZ-ring) · (Rot^(x)8) · (f1 (x) f2) ||^2
// Wave-per-item layout: 256 amps = 64 lanes x 4 regs.
//   amp index a: bit7 = r-bit1, bit3 = r-bit0,
//                bits 6,5,4 = lane bits 5,4,3, bits 2,1,0 = lane bits 2,1,0.
//   -> wires 0,4 are in-register gates; wires 1,2,3,5,6,7 are shfl_xor(32/16/8/4/2/1).
//   -> P_sym pair (7,3) in-register; pairs (6,2),(5,1),(4,0) = shfl_xor(36/18/9).
// One __syncthreads total (gate-matrix publish). No LDS state traffic.

__global__ __launch_bounds__(256) void qattn_kernel(const float* __restrict__ x,
                                                    const float* __restrict__ w,
                                                    float* __restrict__ out) {
    const int tid  = threadIdx.x;
    const int lane = tid & 63;
    const int b    = (blockIdx.x << 2) | (tid >> 6);

    __shared__ float umat[8][8];   // u00r,u00i,u01r,u01i,u10r,u10i,u11r,u11i per wire

    if (tid < 8) {
        const float phi = w[tid * 3 + 0];
        const float th  = w[tid * 3 + 1];
        const float om  = w[tid * 3 + 2];
        float sh, ch;      sincosf(0.5f * th, &sh, &ch);
        float ep_i, ep_r;  sincosf(-0.5f * (phi + om), &ep_i, &ep_r);
        float em_i, em_r;  sincosf( 0.5f * (phi - om), &em_i, &em_r);
        umat[tid][0] =  ep_r * ch;   // u00 = ep*c
        umat[tid][1] =  ep_i * ch;
        umat[tid][2] = -em_r * sh;   // u01 = -em*s
        umat[tid][3] = -em_i * sh;
        umat[tid][4] =  em_r * sh;   // u10 = conj(em)*s
        umat[tid][5] = -em_i * sh;
        umat[tid][6] =  ep_r * ch;   // u11 = conj(ep)*c
        umat[tid][7] = -ep_i * ch;
    }

    // initial amps: a = f1[a>>4] * f2[a&15]; with this layout
    //   f1 idx = ((r>>1)<<3) | (lane>>3),  f2 idx = ((r&1)<<3) | (lane&7)
    const float* xb = x + b * 32;
    const int lh = lane >> 3, ll = lane & 7;
    const float f1a = xb[lh],      f1b = xb[8 + lh];
    const float f2a = xb[16 + ll], f2b = xb[24 + ll];

    float ar[4] = { f1a * f2a, f1a * f2b, f1b * f2a, f1b * f2b };
    float ai[4] = { 0.f, 0.f, 0.f, 0.f };

    __syncthreads();               // umat visible to all 4 waves

    // --- 6 lane-exchange Rot gates: wires {1,2,3,5,6,7} <-> shfl masks {32,16,8,4,2,1}
    const int gw[6] = {1, 2, 3, 5, 6, 7};
    const int gl[6] = {32, 16, 8, 4, 2, 1};
#pragma unroll
    for (int i = 0; i < 6; ++i) {
        const int g = gw[i], L = gl[i];
        const bool hi = (lane & L) != 0;
        const float uar = hi ? umat[g][6] : umat[g][0];   // coeff of own amp
        const float uai = hi ? umat[g][7] : umat[g][1];
        const float ubr = hi ? umat[g][4] : umat[g][2];   // coeff of partner
        const float ubi = hi ? umat[g][5] : umat[g][3];
#pragma unroll
        for (int r = 0; r < 4; ++r) {
            const float pr = __shfl_xor(ar[r], L, 64);
            const float pi = __shfl_xor(ai[r], L, 64);
            const float nr = uar * ar[r] - uai * ai[r] + ubr * pr - ubi * pi;
            const float ni = uar * ai[r] + uai * ar[r] + ubr * pi + ubi * pr;
            ar[r] = nr; ai[r] = ni;
        }
    }

    // --- in-register Rot gates: wire 0 (r-bit1: pairs (0,2),(1,3)), wire 4 (r-bit0: (0,1),(2,3))
    {
        const float u0r=umat[0][0],u0i=umat[0][1],u1r=umat[0][2],u1i=umat[0][3];
        const float u2r=umat[0][4],u2i=umat[0][5],u3r=umat[0][6],u3i=umat[0][7];
#pragma unroll
        for (int lo = 0; lo < 2; ++lo) {
            const int h2 = lo + 2;
            const float a0r=ar[lo],a0i=ai[lo],a1r=ar[h2],a1i=ai[h2];
            ar[lo] = u0r*a0r-u0i*a0i + u1r*a1r-u1i*a1i;
            ai[lo] = u0r*a0i+u0i*a0r + u1r*a1i+u1i*a1r;
            ar[h2] = u2r*a0r-u2i*a0i + u3r*a1r-u3i*a1i;
            ai[h2] = u2r*a0i+u2i*a0r + u3r*a1i+u3i*a1r;
        }
    }
    {
        const float u0r=umat[4][0],u0i=umat[4][1],u1r=umat[4][2],u1i=umat[4][3];
        const float u2r=umat[4][4],u2i=umat[4][5],u3r=umat[4][6],u3i=umat[4][7];
#pragma unroll
        for (int p = 0; p < 2; ++p) {
            const int lo = p * 2, h2 = lo + 1;
            const float a0r=ar[lo],a0i=ai[lo],a1r=ar[h2],a1i=ai[h2];
            ar[lo] = u0r*a0r-u0i*a0i + u1r*a1r-u1i*a1i;
            ai[lo] = u0r*a0i+u0i*a0r + u1r*a1i+u1i*a1r;
            ar[h2] = u2r*a0r-u2i*a0i + u3r*a1r-u3i*a1i;
            ai[h2] = u2r*a0i+u2i*a0r + u3r*a1i+u3i*a1r;
        }
    }

    // --- CZ ring: sign = parity of cyclic adjacent-bit ANDs of amp index
#pragma unroll
    for (int r = 0; r < 4; ++r) {
        const unsigned a = ((unsigned)(r & 2) << 6) | ((unsigned)(lane & 56) << 1)
                         | ((unsigned)(r & 1) << 3) | (unsigned)(lane & 7);
        const unsigned u = ((a >> 1) | (a << 7)) & 0xffu;
        if (__popc(a & u) & 1) { ar[r] = -ar[r]; ai[r] = -ai[r]; }
    }

    // --- P_sym on pair (bit7,bit3): in-register, averages r=1 and r=2
    {
        const float nr = 0.5f * (ar[1] + ar[2]);
        const float ni = 0.5f * (ai[1] + ai[2]);
        ar[1] = ar[2] = nr;  ai[1] = ai[2] = ni;
    }
    // --- P_sym on pairs (6,2),(5,1),(4,0): lane xors 36,18,9
    const int pm[3] = {36, 18, 9};
#pragma unroll
    for (int i = 0; i < 3; ++i) {
        const int L = pm[i];
        const bool diff = __popc(lane & L) & 1;   // the two bits differ
#pragma unroll
        for (int r = 0; r < 4; ++r) {
            const float pr = __shfl_xor(ar[r], L, 64);
            const float pi = __shfl_xor(ai[r], L, 64);
            ar[r] = diff ? 0.5f * (ar[r] + pr) : ar[r];
            ai[r] = diff ? 0.5f * (ai[r] + pi) : ai[r];
        }
    }

    // --- norm^2, wave reduce, write
    float val = 0.f;
#pragma unroll
    for (int r = 0; r < 4; ++r) val += ar[r] * ar[r] + ai[r] * ai[r];
#pragma unroll
    for (int off = 32; off; off >>= 1) val += __shfl_xor(val, off, 64);
    if ((tid & 63) == 0) out[b] = val;
}

extern "C" void kernel_launch(void* const* d_in, const int* in_sizes, int n_in,
                              void* d_out, int out_size, void* d_ws, size_t ws_size,
                              hipStream_t stream) {
    const float* x   = (const float*)d_in[0];   // (2048, 32) f32
    const float* w   = (const float*)d_in[1];   // (1, 8, 3) f32
    float*       out = (float*)d_out;           // (2048,) f32
    qattn_kernel<<<out_size / 4, 256, 0, stream>>>(x, w, out);
}